// Round 5
// baseline (300.611 us; speedup 1.0000x reference)
//
#include <hip/hip_runtime.h>

// PatientMeanEncoder: causal nonzero-mean pool over concat(timesteps, MLP(dem)).
// N=64, L=2048, C_IN=256, DEM=10, hidden 40 -> 20, C_OUT = 276.
//
// R10 == R9 resubmitted verbatim (R9's bench died on GPUAcquisitionTimeout;
// its prediction is still untested, so no new deltas are stacked).
//
// R9: (a) hierarchical k2 prefix. R8's per-wave prefix was an O(S^2) MALL
// burst: 4096 waves x avg 32 segs x 2KB = 256 MB of reads issued at kernel
// start. Now each k2 block owns 4 consecutive segs of one n; its 4 waves
// split the [0,segbase) prefix into quarters, combine via LDS (one barrier),
// then add <=3 remaining partials -> avg ~9 serial iters, 74 MB traffic.
// (b) Regular stores instead of NT: R7 measured WRITE 234 MB vs 145 MB
// output = 1.61x, matching unmerged partial 256B granules from NT stores of
// 1104B rows. MALL arithmetic says allocating stores are safe: at k2 start
// MALL holds ts(134)+part(8)+~114MB dead fill; out-minus-ts drift is 11 MB.
// (c) dem-tail stores batched 32 -> 3 scatter float4 stores (lane r=lane/5,
// chunk j=lane%5; each lane's MLP computes exactly the chunk it stores).
//
// dem channels are constant along l, so causal nonzero-mean == the MLP
// output itself (v>0: (l+1)v/(l+1)=v; v==0: 0/max(0,1)=0).

#define NB 64
#define LL 2048
#define CIN 256
#define COUT 276
#define DEMD 10
#define H1 40
#define H2 20

#define SEGS 64              // segments per patient
#define SROWS (LL / SEGS)    // 32 rows per segment
#define UB 8                 // rows per prefetch batch (8 KB in flight / wave)
#define NBATCH (SROWS / UB)  // 4
#define NUNITS (NB * SEGS)   // 4096 waves
#define NBLK (NUNITS / 4)    // 1024 blocks

// ---------------- kernel 1: per-segment {sum,cnt} partials ----------------
__global__ __launch_bounds__(256) void pme_part(
    const float* __restrict__ ts,   // (N, L, 256)
    float* __restrict__ part)       // (N, SEGS, 256) x {sum, cnt}
{
    const int tid  = threadIdx.x;
    const int w    = tid >> 6;
    const int lane = tid & 63;

    const int unit = blockIdx.x * 4 + w;
    const int seg  = unit & (SEGS - 1);
    const int n    = unit >> 6;

    const float4* tp = (const float4*)(ts + ((size_t)n * LL + seg * SROWS) * CIN) + lane;

    float4 sum = make_float4(0.f, 0.f, 0.f, 0.f);
    float4 ctv = make_float4(0.f, 0.f, 0.f, 0.f);

    float4 v[2][UB];
#pragma unroll
    for (int u = 0; u < UB; ++u)
        v[0][u] = tp[(size_t)u * (CIN / 4)];

    for (int bb = 0; bb < NBATCH; ++bb) {
        const int cur = bb & 1;
        if (bb + 1 < NBATCH) {
#pragma unroll
            for (int u = 0; u < UB; ++u)
                v[cur ^ 1][u] = tp[(size_t)((bb + 1) * UB + u) * (CIN / 4)];
        }
#pragma unroll
        for (int u = 0; u < UB; ++u) {
            float4 x = v[cur][u];
            sum.x += x.x; ctv.x += (x.x != 0.f) ? 1.f : 0.f;
            sum.y += x.y; ctv.y += (x.y != 0.f) ? 1.f : 0.f;
            sum.z += x.z; ctv.z += (x.z != 0.f) ? 1.f : 0.f;
            sum.w += x.w; ctv.w += (x.w != 0.f) ? 1.f : 0.f;
        }
    }

    // interleaved {sum,cnt} per channel pair
    float4* pp = (float4*)part + ((size_t)n * SEGS + seg) * 128 + lane * 2;
    pp[0] = make_float4(sum.x, ctv.x, sum.y, ctv.y);
    pp[1] = make_float4(sum.z, ctv.z, sum.w, ctv.w);
}

// ------- kernel 2: hierarchical prefix + scan + fused dem write -----------
__global__ __launch_bounds__(256) void pme_scan(
    const float* __restrict__ ts,   // (N, L, 256)
    const float* __restrict__ part, // (N, SEGS, 256) x {sum, cnt}
    const float* __restrict__ dem,  // (N, 10)
    const float* __restrict__ W1, const float* __restrict__ b1,
    const float* __restrict__ W2, const float* __restrict__ b2,
    float* __restrict__ out)        // (N, L, 276)
{
    __shared__ float4 QS[4][64];    // quarter prefix sums, pair A (4 KB)
    __shared__ float4 QC[4][64];    // quarter prefix sums, pair B (4 KB)

    const int tid  = threadIdx.x;
    const int w    = tid >> 6;
    const int lane = tid & 63;

    const int b       = blockIdx.x;
    const int n       = b >> 4;          // 16 blocks per patient
    const int grp     = b & 15;
    const int segbase = grp * 4;
    const int seg     = segbase + w;
    const int q       = grp;             // quarter length = segbase/4

    const float4* base = (const float4*)part + (size_t)n * SEGS * 128 + lane * 2;

    // ---- quarter sums: wave w covers partials [w*q, w*q+q) ----
    float4 A = make_float4(0.f, 0.f, 0.f, 0.f);
    float4 B = make_float4(0.f, 0.f, 0.f, 0.f);
    for (int s = w * q; s < w * q + q; ++s) {   // wave-uniform trip count
        float4 a = base[(size_t)s * 128];
        float4 c = base[(size_t)s * 128 + 1];
        A.x += a.x; A.y += a.y; A.z += a.z; A.w += a.w;
        B.x += c.x; B.y += c.y; B.z += c.z; B.w += c.w;
    }
    QS[w][lane] = A;
    QC[w][lane] = B;
    __syncthreads();

    A = make_float4(0.f, 0.f, 0.f, 0.f);
    B = make_float4(0.f, 0.f, 0.f, 0.f);
#pragma unroll
    for (int s = 0; s < 4; ++s) {
        float4 a = QS[s][lane];
        float4 c = QC[s][lane];
        A.x += a.x; A.y += a.y; A.z += a.z; A.w += a.w;
        B.x += c.x; B.y += c.y; B.z += c.z; B.w += c.w;
    }
    for (int s = segbase; s < seg; ++s) {       // <=3 extra partials
        float4 a = base[(size_t)s * 128];
        float4 c = base[(size_t)s * 128 + 1];
        A.x += a.x; A.y += a.y; A.z += a.z; A.w += a.w;
        B.x += c.x; B.y += c.y; B.z += c.z; B.w += c.w;
    }
    float4 acc = make_float4(A.x, A.z, B.x, B.z);
    float4 cnt = make_float4(A.y, A.w, B.y, B.w);

    // ---- dem MLP: lane computes the chunk (lane%5) it will store ----
    const int tr = lane / 5;        // tail row within group (0..12)
    const int tj = lane - tr * 5;   // tail chunk (0..4)
    float4 e4q;
    {
        const float* dn = dem + n * DEMD;
        float d[DEMD];
#pragma unroll
        for (int i = 0; i < DEMD; ++i)
            d[i] = dn[i];
        float e0 = b2[tj * 4 + 0], e1 = b2[tj * 4 + 1], e2 = b2[tj * 4 + 2], e3 = b2[tj * 4 + 3];
#pragma unroll
        for (int k = 0; k < H1; ++k) {
            float hk = b1[k];
#pragma unroll
            for (int i = 0; i < DEMD; ++i)
                hk += d[i] * W1[i * H1 + k];
            hk = fmaxf(hk, 0.f);
            e0 += hk * W2[k * H2 + tj * 4 + 0];
            e1 += hk * W2[k * H2 + tj * 4 + 1];
            e2 += hk * W2[k * H2 + tj * 4 + 2];
            e3 += hk * W2[k * H2 + tj * 4 + 3];
        }
        e4q = make_float4(fmaxf(e0, 0.f), fmaxf(e1, 0.f), fmaxf(e2, 0.f), fmaxf(e3, 0.f));
    }

    // ---- stream 32 rows (MALL-resident), scan, regular stores ----
    const float4* tp = (const float4*)(ts + ((size_t)n * LL + seg * SROWS) * CIN) + lane;
    float* oprow = out + ((size_t)n * LL + seg * SROWS) * COUT;

    float4 v[2][UB];
#pragma unroll
    for (int u = 0; u < UB; ++u)
        v[0][u] = tp[(size_t)u * (CIN / 4)];

    for (int bb = 0; bb < NBATCH; ++bb) {
        const int cur = bb & 1;
        if (bb + 1 < NBATCH) {
#pragma unroll
            for (int u = 0; u < UB; ++u)
                v[cur ^ 1][u] = tp[(size_t)((bb + 1) * UB + u) * (CIN / 4)];
        }
#pragma unroll
        for (int u = 0; u < UB; ++u) {
            float4 x = v[cur][u];
            float4 r;
            acc.x += x.x; cnt.x += (x.x != 0.f) ? 1.f : 0.f;
            acc.y += x.y; cnt.y += (x.y != 0.f) ? 1.f : 0.f;
            acc.z += x.z; cnt.z += (x.z != 0.f) ? 1.f : 0.f;
            acc.w += x.w; cnt.w += (x.w != 0.f) ? 1.f : 0.f;
            r.x = fmaxf(acc.x * __builtin_amdgcn_rcpf(fmaxf(cnt.x, 1.f)), 0.f);
            r.y = fmaxf(acc.y * __builtin_amdgcn_rcpf(fmaxf(cnt.y, 1.f)), 0.f);
            r.z = fmaxf(acc.z * __builtin_amdgcn_rcpf(fmaxf(cnt.z, 1.f)), 0.f);
            r.w = fmaxf(acc.w * __builtin_amdgcn_rcpf(fmaxf(cnt.w, 1.f)), 0.f);
            *(float4*)(oprow + (size_t)(bb * UB + u) * COUT + lane * 4) = r;
        }
    }

    // ---- dem tails: 3 scatter stores cover all 32 rows (12+12+8) ----
    float* tailbase = oprow + CIN;
    if (lane < 60) {
        *(float4*)(tailbase + (size_t)(0  + tr) * COUT + tj * 4) = e4q;
        *(float4*)(tailbase + (size_t)(12 + tr) * COUT + tj * 4) = e4q;
    }
    if (lane < 40)
        *(float4*)(tailbase + (size_t)(24 + tr) * COUT + tj * 4) = e4q;
}

extern "C" void kernel_launch(void* const* d_in, const int* in_sizes, int n_in,
                              void* d_out, int out_size, void* d_ws, size_t ws_size,
                              hipStream_t stream) {
    const float* ts  = (const float*)d_in[0];
    const float* dem = (const float*)d_in[1];
    const float* W1  = (const float*)d_in[2];
    const float* b1  = (const float*)d_in[3];
    const float* W2  = (const float*)d_in[4];
    const float* b2  = (const float*)d_in[5];
    float* out  = (float*)d_out;
    float* part = (float*)d_ws;   // 64*64*256*2 floats = 8.39 MB

    pme_part<<<NBLK, 256, 0, stream>>>(ts, part);
    pme_scan<<<NBLK, 256, 0, stream>>>(ts, part, dem, W1, b1, W2, b2, out);
}